// Round 1
// baseline (205.478 us; speedup 1.0000x reference)
//
#include <hip/hip_runtime.h>
#include <math.h>

#define B_DIM 8
#define T_DIM 1024
#define D_DIM 512
#define BT (B_DIM * T_DIM)   // 8192
#define POS_HALF 4
#define NEG_LEN 12
#define NBLK2 4096           // loss_kernel blocks (16384 waves / 4)

// ws layout (floats):
//   [0, 8192)            inv_m
//   [8192, 16384)        inv_a
//   [16384, 20480)       per-block partial loss   (4096)
//   [20480, 24576)       per-block partial correct (4096)

__device__ __forceinline__ float wave_reduce_sum(float v) {
#pragma unroll
    for (int off = 32; off > 0; off >>= 1) v += __shfl_xor(v, off, 64);
    return v;
}

__global__ __launch_bounds__(256) void norm_kernel(
    const float* __restrict__ m, const float* __restrict__ a,
    float* __restrict__ invm, float* __restrict__ inva)
{
    int wid  = blockIdx.x * 4 + (threadIdx.x >> 6);   // row in [0, 8192)
    int lane = threadIdx.x & 63;
    const float4* mr = (const float4*)(m + (size_t)wid * D_DIM);
    const float4* ar = (const float4*)(a + (size_t)wid * D_DIM);
    float4 m0 = mr[lane], m1 = mr[lane + 64];
    float4 a0 = ar[lane], a1 = ar[lane + 64];
    float sm = m0.x*m0.x + m0.y*m0.y + m0.z*m0.z + m0.w*m0.w
             + m1.x*m1.x + m1.y*m1.y + m1.z*m1.z + m1.w*m1.w;
    float sa = a0.x*a0.x + a0.y*a0.y + a0.z*a0.z + a0.w*a0.w
             + a1.x*a1.x + a1.y*a1.y + a1.z*a1.z + a1.w*a1.w;
    sm = wave_reduce_sum(sm);
    sa = wave_reduce_sum(sa);
    if (lane == 0) {
        invm[wid] = 1.0f / fmaxf(sqrtf(sm), 1e-12f);
        inva[wid] = 1.0f / fmaxf(sqrtf(sa), 1e-12f);
    }
}

__global__ __launch_bounds__(256) void loss_kernel(
    const float* __restrict__ m, const float* __restrict__ a,
    const float* __restrict__ invm, const float* __restrict__ inva,
    const float* __restrict__ pscale, const float* __restrict__ pbias,
    float* __restrict__ part_loss, float* __restrict__ part_corr)
{
    int warp = threadIdx.x >> 6;
    int lane = threadIdx.x & 63;
    int wid  = blockIdx.x * 4 + warp;     // [0, 16384)
    int dir  = wid >> 13;                 // 0: q=m,kv=a ; 1: q=a,kv=m
    int bt   = wid & (BT - 1);            // b*T + t   (t fastest -> L1 reuse)
    int t    = bt & (T_DIM - 1);
    int brow = bt - t;                    // b*T

    const float* q     = dir ? a    : m;
    const float* kv    = dir ? m    : a;
    const float* invq  = dir ? inva : invm;
    const float* invkv = dir ? invm : inva;

    float scale = expf(pscale[0]);
    float bias  = pbias[0];

    const float4* qr = (const float4*)(q + (size_t)bt * D_DIM);
    float4 q0 = qr[lane], q1 = qr[lane + 64];
    float iq = invq[bt] * scale;          // fold scale into q's inv-norm

    int start = max(0, t - POS_HALF);
    int end   = min(T_DIM, t + POS_HALF);
    int lo    = max(0, start - NEG_LEN);
    int hi    = min(T_DIM, end + NEG_LEN);

    float loss = 0.0f;
    float maxv = -INFINITY;
    int   maxpos = 0;

    for (int j = lo; j < hi; ++j) {
        const float4* kr = (const float4*)(kv + (size_t)(brow + j) * D_DIM);
        float4 k0 = kr[lane], k1 = kr[lane + 64];
        float p = q0.x*k0.x + q0.y*k0.y + q0.z*k0.z + q0.w*k0.w
                + q1.x*k1.x + q1.y*k1.y + q1.z*k1.z + q1.w*k1.w;
        p = wave_reduce_sum(p);           // all lanes get the full dot
        float logit = p * iq * invkv[brow + j] + bias;
        bool  pos = (j >= start) && (j < end);
        float y = pos ? -logit : logit;   // y = -sign*logit
        // -log_sigmoid(sign*logit) = softplus(y), numerically stable:
        loss += fmaxf(y, 0.0f) + log1pf(expf(-fabsf(y)));
        if (logit > maxv) { maxv = logit; maxpos = pos ? 1 : 0; }
    }

    __shared__ float sh_loss[4];
    __shared__ float sh_corr[4];
    if (lane == 0) { sh_loss[warp] = loss; sh_corr[warp] = (float)maxpos; }
    __syncthreads();
    if (threadIdx.x == 0) {
        part_loss[blockIdx.x] = sh_loss[0] + sh_loss[1] + sh_loss[2] + sh_loss[3];
        part_corr[blockIdx.x] = sh_corr[0] + sh_corr[1] + sh_corr[2] + sh_corr[3];
    }
}

__global__ __launch_bounds__(256) void finalize_kernel(
    const float* __restrict__ part_loss, const float* __restrict__ part_corr,
    float* __restrict__ out)
{
    int tid = threadIdx.x;
    float sl = 0.0f, sc = 0.0f;
    for (int i = tid; i < NBLK2; i += 256) { sl += part_loss[i]; sc += part_corr[i]; }
    sl = wave_reduce_sum(sl);
    sc = wave_reduce_sum(sc);
    __shared__ float shl[4], shc[4];
    int warp = tid >> 6, lane = tid & 63;
    if (lane == 0) { shl[warp] = sl; shc[warp] = sc; }
    __syncthreads();
    if (tid == 0) {
        float L = shl[0] + shl[1] + shl[2] + shl[3];
        float C = shc[0] + shc[1] + shc[2] + shc[3];
        out[0] = L / 16384.0f;   // (m2a+a2m)/(2T) with mean over B folded in
        out[1] = C / 16384.0f;   // (m2a+a2m)/(2*T*B)
    }
}

extern "C" void kernel_launch(void* const* d_in, const int* in_sizes, int n_in,
                              void* d_out, int out_size, void* d_ws, size_t ws_size,
                              hipStream_t stream)
{
    const float* m  = (const float*)d_in[0];
    const float* a  = (const float*)d_in[1];
    const float* ps = (const float*)d_in[2];
    const float* pb = (const float*)d_in[3];
    float* ws = (float*)d_ws;
    float* invm      = ws;
    float* inva      = ws + BT;
    float* part_loss = ws + 2 * BT;
    float* part_corr = ws + 2 * BT + NBLK2;
    float* out = (float*)d_out;

    norm_kernel<<<BT / 4, 256, 0, stream>>>(m, a, invm, inva);
    loss_kernel<<<NBLK2, 256, 0, stream>>>(m, a, invm, inva, ps, pb,
                                           part_loss, part_corr);
    finalize_kernel<<<1, 256, 0, stream>>>(part_loss, part_corr, out);
}

// Round 2
// 96.875 us; speedup vs baseline: 2.1211x; 2.1211x over previous
//
#include <hip/hip_runtime.h>
#include <math.h>

#define B_DIM 8
#define T_DIM 1024
#define D_DIM 512
#define BT (B_DIM * T_DIM)   // 8192
#define GSTRIDE 40           // band row stride (33 used, padded)
#define NBLK3 2048           // loss3 blocks
#define NBLK_OLD 4096        // fallback path blocks

typedef __bf16 bf16x8 __attribute__((ext_vector_type(8)));
typedef float floatx4 __attribute__((ext_vector_type(4)));

__device__ __forceinline__ float wave_reduce_sum(float v) {
#pragma unroll
    for (int off = 32; off > 0; off >>= 1) v += __shfl_xor(v, off, 64);
    return v;
}

// fp32 -> bf16 round-to-nearest-even
__device__ __forceinline__ ushort f2bf(float x) {
    unsigned u = __float_as_uint(x);
    unsigned r = (u + 0x7fffu + ((u >> 16) & 1u)) >> 16;
    return (ushort)r;
}

// ---------------- Phase 1: normalize + convert to bf16 ----------------
__global__ __launch_bounds__(256) void prep_kernel(
    const float* __restrict__ m, const float* __restrict__ a,
    ushort* __restrict__ mhat, ushort* __restrict__ ahat)
{
    int wid  = blockIdx.x * 4 + (threadIdx.x >> 6);   // row in [0, 8192)
    int lane = threadIdx.x & 63;
    const float4* mr = (const float4*)(m + (size_t)wid * D_DIM);
    const float4* ar = (const float4*)(a + (size_t)wid * D_DIM);
    float4 m0 = mr[lane], m1 = mr[lane + 64];
    float4 a0 = ar[lane], a1 = ar[lane + 64];
    float sm = m0.x*m0.x + m0.y*m0.y + m0.z*m0.z + m0.w*m0.w
             + m1.x*m1.x + m1.y*m1.y + m1.z*m1.z + m1.w*m1.w;
    float sa = a0.x*a0.x + a0.y*a0.y + a0.z*a0.z + a0.w*a0.w
             + a1.x*a1.x + a1.y*a1.y + a1.z*a1.z + a1.w*a1.w;
    sm = wave_reduce_sum(sm);
    sa = wave_reduce_sum(sa);
    float im = 1.0f / fmaxf(sqrtf(sm), 1e-12f);
    float ia = 1.0f / fmaxf(sqrtf(sa), 1e-12f);
    ushort4 mo0 = { f2bf(m0.x*im), f2bf(m0.y*im), f2bf(m0.z*im), f2bf(m0.w*im) };
    ushort4 mo1 = { f2bf(m1.x*im), f2bf(m1.y*im), f2bf(m1.z*im), f2bf(m1.w*im) };
    ushort4 ao0 = { f2bf(a0.x*ia), f2bf(a0.y*ia), f2bf(a0.z*ia), f2bf(a0.w*ia) };
    ushort4 ao1 = { f2bf(a1.x*ia), f2bf(a1.y*ia), f2bf(a1.z*ia), f2bf(a1.w*ia) };
    ushort4* mw = (ushort4*)(mhat + (size_t)wid * D_DIM);
    ushort4* aw = (ushort4*)(ahat + (size_t)wid * D_DIM);
    mw[lane] = mo0; mw[lane + 64] = mo1;
    aw[lane] = ao0; aw[lane + 64] = ao1;
}

// ---------------- Phase 2: banded Gram matrix via MFMA ----------------
// Block = (b, t0). Computes G[t, c] = mhat_t . ahat_c for t in [t0,t0+16),
// c in [t0-16, t0+32). Stores band diagonals d = c-t+16 in [0,32].
__global__ __launch_bounds__(256) void band_kernel(
    const ushort* __restrict__ mhat, const ushort* __restrict__ ahat,
    float* __restrict__ gband)
{
    int blk = blockIdx.x;                 // 512 blocks
    int b   = blk >> 6;
    int t0  = (blk & 63) << 4;
    int w    = threadIdx.x >> 6;          // wave id: k-split
    int lane = threadIdx.x & 63;
    int mrow = lane & 15;                 // fragment row (m or n index)
    int kgrp = lane >> 4;                 // k-group within fragment

    const ushort* Abase = mhat + ((size_t)b << 19);   // b*1024*512
    const ushort* Bbase = ahat + ((size_t)b << 19);
    int koff = w * 128 + kgrp * 8;

    const ushort* arow = Abase + (size_t)(t0 + mrow) * D_DIM + koff;
    int j0 = max(t0 - 16 + mrow, 0);
    int j1 = t0 + mrow;
    int j2 = min(t0 + 16 + mrow, T_DIM - 1);
    const ushort* br0 = Bbase + (size_t)j0 * D_DIM + koff;
    const ushort* br1 = Bbase + (size_t)j1 * D_DIM + koff;
    const ushort* br2 = Bbase + (size_t)j2 * D_DIM + koff;

    floatx4 acc0 = {0.f,0.f,0.f,0.f};
    floatx4 acc1 = {0.f,0.f,0.f,0.f};
    floatx4 acc2 = {0.f,0.f,0.f,0.f};
#pragma unroll
    for (int ks = 0; ks < 4; ++ks) {
        bf16x8 af = *(const bf16x8*)(arow + ks * 32);
        bf16x8 b0 = *(const bf16x8*)(br0 + ks * 32);
        bf16x8 b1 = *(const bf16x8*)(br1 + ks * 32);
        bf16x8 b2 = *(const bf16x8*)(br2 + ks * 32);
        acc0 = __builtin_amdgcn_mfma_f32_16x16x32_bf16(af, b0, acc0, 0, 0, 0);
        acc1 = __builtin_amdgcn_mfma_f32_16x16x32_bf16(af, b1, acc1, 0, 0, 0);
        acc2 = __builtin_amdgcn_mfma_f32_16x16x32_bf16(af, b2, acc2, 0, 0, 0);
    }

    // cross-wave (k-split) reduction in LDS.
    // C layout: col = lane&15, row = (lane>>4)*4 + reg   [guide §3, m89]
    __shared__ float red[4][3][256];
#pragma unroll
    for (int r = 0; r < 4; ++r) {
        int rr = (kgrp * 4 + r) * 16 + mrow;
        red[w][0][rr] = acc0[r];
        red[w][1][rr] = acc1[r];
        red[w][2][rr] = acc2[r];
    }
    __syncthreads();

    int i  = threadIdx.x >> 4;   // local row (t - t0)
    int cc = threadIdx.x & 15;   // col within j-tile
#pragma unroll
    for (int jt = 0; jt < 3; ++jt) {
        float s = red[0][jt][threadIdx.x] + red[1][jt][threadIdx.x]
                + red[2][jt][threadIdx.x] + red[3][jt][threadIdx.x];
        int d = jt * 16 + cc - i;          // c - t + 16
        if (d >= 0 && d <= 32)
            gband[(size_t)((b << 10) + t0 + i) * GSTRIDE + d] = s;
    }
}

// ---------------- Phase 3: band -> both losses + accuracy ----------------
__global__ __launch_bounds__(256) void loss3_kernel(
    const float* __restrict__ gband,
    const float* __restrict__ pscale, const float* __restrict__ pbias,
    float* __restrict__ part_loss, float* __restrict__ part_corr)
{
    int warp = threadIdx.x >> 6, lane = threadIdx.x & 63;
    int wid = blockIdx.x * 4 + warp;      // (b,t) in [0, 8192)
    int b = wid >> 10, t = wid & 1023;
    float scale = expf(pscale[0]), bias = pbias[0];

    float loss = 0.0f;
    float mv = -1e30f, av = -1e30f;
    int mp = 0, ap = 0;

    if (lane < 32) {
        // m2a: logit for col c = t-16+lane is band[t][lane]
        int c = t - 16 + lane;
        if (c >= 0 && c < T_DIM) {
            float logit = gband[(size_t)wid * GSTRIDE + lane] * scale + bias;
            bool pos = (c >= t - 4) && (c < t + 4);
            float y = pos ? -logit : logit;
            loss = fmaxf(y, 0.0f) + log1pf(expf(-fabsf(y)));
            mv = logit; mp = pos ? 1 : 0;
        }
    } else {
        // a2m: logit a_t.m_r for r = t+o, o = lane-48 in [-16,16);
        // equals G[r][t] = band[r][16-o]
        int o = lane - 48;
        int r = t + o;
        if (r >= 0 && r < T_DIM) {
            float logit = gband[(size_t)((b << 10) + r) * GSTRIDE + (16 - o)] * scale + bias;
            bool pos = (r >= t - 4) && (r < t + 4);
            float y = pos ? -logit : logit;
            loss = fmaxf(y, 0.0f) + log1pf(expf(-fabsf(y)));
            av = logit; ap = pos ? 1 : 0;
        }
    }

    loss = wave_reduce_sum(loss);
#pragma unroll
    for (int off = 32; off > 0; off >>= 1) {
        float ov = __shfl_xor(mv, off, 64); int op = __shfl_xor(mp, off, 64);
        if (ov > mv) { mv = ov; mp = op; }
        float o2 = __shfl_xor(av, off, 64); int p2 = __shfl_xor(ap, off, 64);
        if (o2 > av) { av = o2; ap = p2; }
    }

    __shared__ float shl[4], shc[4];
    if (lane == 0) { shl[warp] = loss; shc[warp] = (float)(mp + ap); }
    __syncthreads();
    if (threadIdx.x == 0) {
        part_loss[blockIdx.x] = shl[0] + shl[1] + shl[2] + shl[3];
        part_corr[blockIdx.x] = shc[0] + shc[1] + shc[2] + shc[3];
    }
}

__global__ __launch_bounds__(256) void finalize3_kernel(
    const float* __restrict__ part_loss, const float* __restrict__ part_corr,
    float* __restrict__ out)
{
    int tid = threadIdx.x;
    float sl = 0.0f, sc = 0.0f;
    for (int i = tid; i < NBLK3; i += 256) { sl += part_loss[i]; sc += part_corr[i]; }
    sl = wave_reduce_sum(sl);
    sc = wave_reduce_sum(sc);
    __shared__ float shl[4], shc[4];
    int warp = tid >> 6, lane = tid & 63;
    if (lane == 0) { shl[warp] = sl; shc[warp] = sc; }
    __syncthreads();
    if (tid == 0) {
        out[0] = (shl[0] + shl[1] + shl[2] + shl[3]) / 16384.0f;
        out[1] = (shc[0] + shc[1] + shc[2] + shc[3]) / 16384.0f;
    }
}

// ---------------- Fallback path (round-1 vector kernels) ----------------
__global__ __launch_bounds__(256) void norm_kernel(
    const float* __restrict__ m, const float* __restrict__ a,
    float* __restrict__ invm, float* __restrict__ inva)
{
    int wid  = blockIdx.x * 4 + (threadIdx.x >> 6);
    int lane = threadIdx.x & 63;
    const float4* mr = (const float4*)(m + (size_t)wid * D_DIM);
    const float4* ar = (const float4*)(a + (size_t)wid * D_DIM);
    float4 m0 = mr[lane], m1 = mr[lane + 64];
    float4 a0 = ar[lane], a1 = ar[lane + 64];
    float sm = m0.x*m0.x + m0.y*m0.y + m0.z*m0.z + m0.w*m0.w
             + m1.x*m1.x + m1.y*m1.y + m1.z*m1.z + m1.w*m1.w;
    float sa = a0.x*a0.x + a0.y*a0.y + a0.z*a0.z + a0.w*a0.w
             + a1.x*a1.x + a1.y*a1.y + a1.z*a1.z + a1.w*a1.w;
    sm = wave_reduce_sum(sm);
    sa = wave_reduce_sum(sa);
    if (lane == 0) {
        invm[wid] = 1.0f / fmaxf(sqrtf(sm), 1e-12f);
        inva[wid] = 1.0f / fmaxf(sqrtf(sa), 1e-12f);
    }
}

__global__ __launch_bounds__(256) void loss_kernel(
    const float* __restrict__ m, const float* __restrict__ a,
    const float* __restrict__ invm, const float* __restrict__ inva,
    const float* __restrict__ pscale, const float* __restrict__ pbias,
    float* __restrict__ part_loss, float* __restrict__ part_corr)
{
    int warp = threadIdx.x >> 6;
    int lane = threadIdx.x & 63;
    int wid  = blockIdx.x * 4 + warp;
    int dir  = wid >> 13;
    int bt   = wid & (BT - 1);
    int t    = bt & (T_DIM - 1);
    int brow = bt - t;

    const float* q     = dir ? a    : m;
    const float* kv    = dir ? m    : a;
    const float* invq  = dir ? inva : invm;
    const float* invkv = dir ? invm : inva;

    float scale = expf(pscale[0]);
    float bias  = pbias[0];

    const float4* qr = (const float4*)(q + (size_t)bt * D_DIM);
    float4 q0 = qr[lane], q1 = qr[lane + 64];
    float iq = invq[bt] * scale;

    int start = max(0, t - 4);
    int end   = min(T_DIM, t + 4);
    int lo    = max(0, start - 12);
    int hi    = min(T_DIM, end + 12);

    float loss = 0.0f;
    float maxv = -INFINITY;
    int   maxpos = 0;

    for (int j = lo; j < hi; ++j) {
        const float4* kr = (const float4*)(kv + (size_t)(brow + j) * D_DIM);
        float4 k0 = kr[lane], k1 = kr[lane + 64];
        float p = q0.x*k0.x + q0.y*k0.y + q0.z*k0.z + q0.w*k0.w
                + q1.x*k1.x + q1.y*k1.y + q1.z*k1.z + q1.w*k1.w;
        p = wave_reduce_sum(p);
        float logit = p * iq * invkv[brow + j] + bias;
        bool  pos = (j >= start) && (j < end);
        float y = pos ? -logit : logit;
        loss += fmaxf(y, 0.0f) + log1pf(expf(-fabsf(y)));
        if (logit > maxv) { maxv = logit; maxpos = pos ? 1 : 0; }
    }

    __shared__ float sh_loss[4];
    __shared__ float sh_corr[4];
    if (lane == 0) { sh_loss[warp] = loss; sh_corr[warp] = (float)maxpos; }
    __syncthreads();
    if (threadIdx.x == 0) {
        part_loss[blockIdx.x] = sh_loss[0] + sh_loss[1] + sh_loss[2] + sh_loss[3];
        part_corr[blockIdx.x] = sh_corr[0] + sh_corr[1] + sh_corr[2] + sh_corr[3];
    }
}

__global__ __launch_bounds__(256) void finalize_kernel(
    const float* __restrict__ part_loss, const float* __restrict__ part_corr,
    float* __restrict__ out)
{
    int tid = threadIdx.x;
    float sl = 0.0f, sc = 0.0f;
    for (int i = tid; i < NBLK_OLD; i += 256) { sl += part_loss[i]; sc += part_corr[i]; }
    sl = wave_reduce_sum(sl);
    sc = wave_reduce_sum(sc);
    __shared__ float shl[4], shc[4];
    int warp = tid >> 6, lane = tid & 63;
    if (lane == 0) { shl[warp] = sl; shc[warp] = sc; }
    __syncthreads();
    if (tid == 0) {
        out[0] = (shl[0] + shl[1] + shl[2] + shl[3]) / 16384.0f;
        out[1] = (shc[0] + shc[1] + shc[2] + shc[3]) / 16384.0f;
    }
}

extern "C" void kernel_launch(void* const* d_in, const int* in_sizes, int n_in,
                              void* d_out, int out_size, void* d_ws, size_t ws_size,
                              hipStream_t stream)
{
    const float* m  = (const float*)d_in[0];
    const float* a  = (const float*)d_in[1];
    const float* ps = (const float*)d_in[2];
    const float* pb = (const float*)d_in[3];
    float* out = (float*)d_out;

    // MFMA path workspace: mhat(8MB) + ahat(8MB) + gband(1.31MB) + partials
    const size_t MHAT_ELEMS = (size_t)BT * D_DIM;            // ushorts
    const size_t GBAND_ELEMS = (size_t)BT * GSTRIDE;         // floats
    size_t need = MHAT_ELEMS * 2 * sizeof(ushort)
                + GBAND_ELEMS * sizeof(float)
                + 2 * NBLK3 * sizeof(float);

    if (ws_size >= need) {
        ushort* mhat = (ushort*)d_ws;
        ushort* ahat = mhat + MHAT_ELEMS;
        float*  gband = (float*)(ahat + MHAT_ELEMS);
        float*  part_loss = gband + GBAND_ELEMS;
        float*  part_corr = part_loss + NBLK3;

        prep_kernel<<<BT / 4, 256, 0, stream>>>(m, a, mhat, ahat);
        band_kernel<<<B_DIM * (T_DIM / 16), 256, 0, stream>>>(mhat, ahat, gband);
        loss3_kernel<<<NBLK3, 256, 0, stream>>>(gband, ps, pb, part_loss, part_corr);
        finalize3_kernel<<<1, 256, 0, stream>>>(part_loss, part_corr, out);
    } else {
        float* ws = (float*)d_ws;
        float* invm      = ws;
        float* inva      = ws + BT;
        float* part_loss = ws + 2 * BT;
        float* part_corr = ws + 2 * BT + NBLK_OLD;

        norm_kernel<<<BT / 4, 256, 0, stream>>>(m, a, invm, inva);
        loss_kernel<<<NBLK_OLD, 256, 0, stream>>>(m, a, invm, inva, ps, pb,
                                                  part_loss, part_corr);
        finalize_kernel<<<1, 256, 0, stream>>>(part_loss, part_corr, out);
    }
}